// Round 14
// baseline (117.676 us; speedup 1.0000x reference)
//
#include <hip/hip_runtime.h>

// BarrierNet fused MLP + CBF-QP filter — output-transposed f16 MFMA,
// no-transpose dataflow, ALL weights in LDS, pair-rcp silu, 4-chain ILP,
// 3 waves/EU.
//
// Cross-round findings:
//  * VALU/trans issue per tile is the fixed budget (48 silu/lane/tile);
//    wall time tracks issue *density* = resident waves x chains/wave.
//  * NT=4 failed in R8/R11 ONLY because weights held 104 VGPRs (residency
//    crushed to 2 waves/SIMD) or LDS-tile addressing blew L1I. R13 moved
//    all weights to LDS (26.9 KB, staged once) — both blockers gone.
//  * R12/R13 (LDS weights, pair-rcp): kernel <42us, best so far.
//
// R14: NT=4 chains/wave at __launch_bounds__(256,3): per-chain peak ~35
// regs (xf dies after L1; b2f+acc2 overlap only in L2), 4 chains + misc
// ~155 regs < 170 budget. 3 waves x 4 chains = 12 concurrent chains/SIMD
// (vs 8), and each LDS weight fragment read feeds 4 MFMAs.
// WRITE_SIZE is the spill tripwire (R3/R5: over-tight bound -> scratch).
//
// Dataflow (R10): D = W·X^T via mfma(Wfrag, Xfrag); next layer's B-frag
// built IN-LANE from C-layout accs via H-permuted prepacked weights
// (H(kt,q,j) = (2kt+(j>>2))*16 + q*4 + (j&3)); L1 bias in k=10 pad slot;
// L3 heads land u0,u1,z32 in q==0 lanes -> register epilogue. silu via
// pair-rcp (one v_rcp per two sigmoids; exp arg clamped <=30: no inf*0).
//
// Layouts (HW-verified, learn_hip m89/m91/m120):
//   A-frag: lane holds A[m=lane&15][k=(lane>>4)*8 + j], j=0..7
//   B-frag: lane holds B[k=(lane>>4)*8+j][n=lane&15]
//   C/D   : lane holds D[row=(lane>>4)*4+reg][col=lane&15]

typedef _Float16 half8 __attribute__((ext_vector_type(8)));
typedef float floatx4 __attribute__((ext_vector_type(4)));

#define TPB 256
#define NW  4          // waves per block
#define NT  4          // chains (16-row tiles) per wave

// d_ws layout (bytes). Fragments: half8[fragID][lane]; fragID 0..7 = W1
// n-tiles (k=10 slot carries b1), 8..23 = W2 (nt2*4+kt, H-permuted k),
// 24..25 = W3 heads (H-permuted k). Then bias table for L2 C-init.
#define WS_FRAG 0        // 26*64 half8 = 26624 B
#define WS_B2Q  26624    // 16 float4  =   256 B   [nt2][q] -> {bias r=0..3}
#define WS_END  26880    // bytes staged into LDS (= 1680 float4)

__device__ __forceinline__ float fast_sigmoid(float z) {
    return __builtin_amdgcn_rcpf(1.0f + __expf(-z));
}

// Two silus for one v_rcp: r = 1/(d0*d1); sig0 = r*d1, sig1 = r*d0.
// exp arg clamped to <=30 so d0*d1 stays finite (silu(z<=-30) ~= 0 anyway).
__device__ __forceinline__ void silu_pair(float z0, float z1,
                                          _Float16* o0, _Float16* o1) {
    float e0 = __expf(fminf(-z0, 30.0f));
    float e1 = __expf(fminf(-z1, 30.0f));
    float d0 = 1.0f + e0, d1 = 1.0f + e1;
    float r  = __builtin_amdgcn_rcpf(d0 * d1);
    *o0 = (_Float16)(z0 * d1 * r);
    *o1 = (_Float16)(z1 * d0 * r);
}

// ---------------- prep: fp32 weights -> f16 fragments in ws ----------------
__global__ __launch_bounds__(256) void prep_kernel(
    const float* __restrict__ W1,  const float* __restrict__ b1,
    const float* __restrict__ W21, const float* __restrict__ b21,
    const float* __restrict__ W22, const float* __restrict__ b22,
    const float* __restrict__ W31, const float* __restrict__ b31,
    const float* __restrict__ W32, const float* __restrict__ b32,
    unsigned char* __restrict__ ws)
{
    const int tid  = blockIdx.x * 256 + threadIdx.x;
    const int lane = tid & 63;
    const int m    = lane & 15;
    const int q    = lane >> 4;

    if (tid < 26 * 64) {
        const int f = tid >> 6;
        float v[8];
        if (f < 8) {
            // Ŵ1 A-frag, n-tile f: A[m][k=q*8+j]; k<10 -> W1, k==10 -> b1.
            const float* wr = W1 + (f * 16 + m) * 10;
            #pragma unroll
            for (int j = 0; j < 8; ++j) {
                const int k = q * 8 + j;
                v[j] = (k < 10) ? wr[k] : (k == 10 ? b1[f * 16 + m] : 0.0f);
            }
        } else if (f < 24) {
            // Ŵ2 A-frag (nt2,kt), H-permuted k-order to match in-lane pack.
            const int f2 = f - 8, nt2 = f2 >> 2, kt = f2 & 3;
            const int n2 = nt2 * 16 + m;
            const float* wr = (n2 < 32) ? (W21 + n2 * 128)
                                        : (W22 + (n2 - 32) * 128);
            #pragma unroll
            for (int j = 0; j < 8; ++j) {
                const int H = (2 * kt + (j >> 2)) * 16 + q * 4 + (j & 3);
                v[j] = wr[H];
            }
        } else {
            // Ŵ3 A-frag kt3: rows = heads (u0,u1 from W31; z32 from W32),
            // H3-permuted k-order.
            const int kt3 = f - 24;
            #pragma unroll
            for (int j = 0; j < 8; ++j) {
                const int H3 = (2 * kt3 + (j >> 2)) * 16 + q * 4 + (j & 3);
                float x = 0.0f;
                if (m == 0)      x = (H3 < 32)  ? W31[H3]       : 0.0f;
                else if (m == 1) x = (H3 < 32)  ? W31[32 + H3]  : 0.0f;
                else if (m == 2) x = (H3 >= 32) ? W32[H3 - 32]  : 0.0f;
                v[j] = x;
            }
        }
        half8 h;
        #pragma unroll
        for (int j = 0; j < 8; ++j) h[j] = (_Float16)v[j];
        ((half8*)(ws + WS_FRAG))[tid] = h;
    }
    if (tid < 16) {
        // L2 bias C-init table: [nt2][q] -> bias for out = nt2*16+q*4+r.
        const int nt2 = tid >> 2, qq = tid & 3;
        float4 v;
        float* vp = (float*)&v;
        #pragma unroll
        for (int r = 0; r < 4; ++r) {
            const int n2 = nt2 * 16 + qq * 4 + r;
            vp[r] = (n2 < 32) ? b21[n2] : b22[n2 - 32];
        }
        ((float4*)(ws + WS_B2Q))[tid] = v;
    }
}

// ------------------------------- main -------------------------------------
__global__ __launch_bounds__(TPB, 3) void barriernet_kernel(
    const float* __restrict__ obs,
    const unsigned char* __restrict__ ws,
    const float* __restrict__ b31, const float* __restrict__ b32,
    float* __restrict__ out, int B)
{
    __shared__ __align__(16) unsigned char lds[WS_END];   // all weights

    const int tid  = threadIdx.x;
    const int wave = tid >> 6;
    const int lane = tid & 63;
    const int m    = lane & 15;
    const int q    = lane >> 4;

    // ---- stage full weight image (26.9 KB) into LDS ----
    {
        const float4* src = (const float4*)ws;
        float4* dst = (float4*)lds;
        for (int i = tid; i < WS_END / 16; i += TPB) dst[i] = src[i];
    }
    __syncthreads();   // once; hot path below is barrier-free

    // Fragment f lives at lds + f*1024 + lane*16 (base reg + imm offset).
    const half8*  wl   = ((const half8*)lds) + lane;
    const float4* b2qt = (const float4*)(lds + WS_B2Q);

    const float bu0 = b31[0], bu1 = b31[1], bz3 = b32[0];  // uniform s_loads

    const int tiles = (B + 15) >> 4;
    const int tbase = (blockIdx.x * NW + wave) * NT;

    // --- obs B-fragments for all chains (loads issue back-to-back) ---
    // B-frag: lane (q,m) holds obs[row=m][k=q*8+j]; k=10 slot := 1.0 (bias).
    const float* orow[NT];
    half8 xf[NT];
    int lrow0[NT];
    #pragma unroll
    for (int p = 0; p < NT; ++p) {
        int tile = tbase + p;
        if (tile >= tiles) tile = tiles - 1;            // dup work, benign
        int lr = (tile << 4) + m;
        if (lr >= B) lr = B - 1;
        lrow0[p] = lr;
        orow[p] = obs + (size_t)lr * 10;

        float g0=0,g1=0,g2=0,g3=0,g4=0,g5=0,g6=0,g7=0;
        if (q == 0) {
            float2 p0 = *(const float2*)(orow[p] + 0);
            float2 p1 = *(const float2*)(orow[p] + 2);
            float2 p2 = *(const float2*)(orow[p] + 4);
            float2 p3 = *(const float2*)(orow[p] + 6);
            g0=p0.x; g1=p0.y; g2=p1.x; g3=p1.y;
            g4=p2.x; g5=p2.y; g6=p3.x; g7=p3.y;
        } else if (q == 1) {
            float2 pp = *(const float2*)(orow[p] + 8);
            g0=pp.x; g1=pp.y;
            g2=1.0f;                                   // k=10: bias lane
        }
        xf[p][0]=(_Float16)g0; xf[p][1]=(_Float16)g1;
        xf[p][2]=(_Float16)g2; xf[p][3]=(_Float16)g3;
        xf[p][4]=(_Float16)g4; xf[p][5]=(_Float16)g5;
        xf[p][6]=(_Float16)g6; xf[p][7]=(_Float16)g7;
    }

    // --- layer 1: each W1 fragment pair read ONCE from LDS, feeds all 4
    // chains; fused pair-rcp silu pack (transient accs die immediately) ---
    half8 b2f[NT][4];
    #pragma unroll
    for (int kt = 0; kt < 4; ++kt) {
        half8 w1a = wl[(2 * kt) * 64];                // ds_read_b128, imm off
        half8 w1b = wl[(2 * kt + 1) * 64];
        #pragma unroll
        for (int p = 0; p < NT; ++p) {
            const floatx4 zz = {0.0f, 0.0f, 0.0f, 0.0f};
            floatx4 a0 = __builtin_amdgcn_mfma_f32_16x16x32_f16(
                             w1a, xf[p], zz, 0, 0, 0);
            floatx4 a1 = __builtin_amdgcn_mfma_f32_16x16x32_f16(
                             w1b, xf[p], zz, 0, 0, 0);
            half8 bf;
            #pragma unroll
            for (int jj = 0; jj < 4; ++jj) {
                _Float16 o0, o1;
                silu_pair(a0[jj], a1[jj], &o0, &o1);
                bf[jj] = o0; bf[jj + 4] = o1;
            }
            b2f[p][kt] = bf;
        }
    }

    // --- layer 2: each W2 fragment read ONCE from LDS, feeds all 4 chains;
    // bias C-init read from LDS table ---
    floatx4 acc2[NT][4];
    #pragma unroll
    for (int nt2 = 0; nt2 < 4; ++nt2) {
        float4 bi = b2qt[nt2 * 4 + q];
        floatx4 zi = {bi.x, bi.y, bi.z, bi.w};
        #pragma unroll
        for (int p = 0; p < NT; ++p) acc2[p][nt2] = zi;
        #pragma unroll
        for (int kt = 0; kt < 4; ++kt) {
            half8 wfr = wl[(8 + nt2 * 4 + kt) * 64];  // ds_read_b128, imm off
            #pragma unroll
            for (int p = 0; p < NT; ++p)
                acc2[p][nt2] = __builtin_amdgcn_mfma_f32_16x16x32_f16(
                                   wfr, b2f[p][kt], acc2[p][nt2], 0, 0, 0);
        }
    }

    // --- pair-rcp silu pack to L3 B-fragments ---
    half8 b3f[NT][2];
    #pragma unroll
    for (int kt3 = 0; kt3 < 2; ++kt3) {
        #pragma unroll
        for (int p = 0; p < NT; ++p) {
            half8 bf;
            #pragma unroll
            for (int jj = 0; jj < 4; ++jj) {
                _Float16 o0, o1;
                silu_pair(acc2[p][2 * kt3][jj], acc2[p][2 * kt3 + 1][jj],
                          &o0, &o1);
                bf[jj] = o0; bf[jj + 4] = o1;
            }
            b3f[p][kt3] = bf;
        }
    }

    // --- layer 3 heads + fp32 CBF-QP epilogue straight from registers ---
    half8 w3a = wl[24 * 64];
    half8 w3b = wl[25 * 64];
    #pragma unroll
    for (int p = 0; p < NT; ++p) {
        floatx4 d = {0.0f, 0.0f, 0.0f, 0.0f};
        d = __builtin_amdgcn_mfma_f32_16x16x32_f16(w3a, b3f[p][0], d, 0, 0, 0);
        d = __builtin_amdgcn_mfma_f32_16x16x32_f16(w3b, b3f[p][1], d, 0, 0, 0);
        // D[head=q*4+r][row=m]: q==0 lanes hold u0(r0), u1(r1), z32(r2).
        if (q == 0) {
            const float u0  = d[0] + bu0;
            const float u1  = d[1] + bu1;
            const float z32 = d[2] + bz3;
            const float alpha = 4.0f * fast_sigmoid(z32);

            const float2 rxy = *(const float2*)(orow[p] + 6);
            const float2 vxy = *(const float2*)(orow[p] + 8);
            const float rx = rxy.x, ry = rxy.y, vx = vxy.x, vy = vxy.y;

            const float barrier = rx * rx + ry * ry - 0.64f;   // R_SAFE^2
            const float lf = -2.0f * (rx * vx + ry * vy);
            const float gx = -2.0f * rx, gy = -2.0f * ry;
            const float h  = lf + alpha * barrier;
            const float gg = gx * gx + gy * gy;
            const float viol = gx * u0 + gy * u1 - h;
            float lam = 0.0f;
            if (gg > 0.0f)
                lam = fmaxf(viol, 0.0f) *
                      __builtin_amdgcn_rcpf(fmaxf(gg, 1e-12f));

            float2 r;
            r.x = fmaf(-lam, gx, u0);
            r.y = fmaf(-lam, gy, u1);
            *(float2*)(out + (size_t)lrow0[p] * 2) = r;   // 16 rows, coalesced
        }
    }
}

extern "C" void kernel_launch(void* const* d_in, const int* in_sizes, int n_in,
                              void* d_out, int out_size, void* d_ws, size_t ws_size,
                              hipStream_t stream) {
    const float* obs = (const float*)d_in[0];
    const float* W1  = (const float*)d_in[1];
    const float* b1  = (const float*)d_in[2];
    const float* W21 = (const float*)d_in[3];
    const float* b21 = (const float*)d_in[4];
    const float* W22 = (const float*)d_in[5];
    const float* b22 = (const float*)d_in[6];
    const float* W31 = (const float*)d_in[7];
    const float* b31 = (const float*)d_in[8];
    const float* W32 = (const float*)d_in[9];
    const float* b32 = (const float*)d_in[10];

    unsigned char* ws = (unsigned char*)d_ws;

    prep_kernel<<<7, 256, 0, stream>>>(W1, b1, W21, b21, W22, b22,
                                       W31, b31, W32, b32, ws);

    const int B = in_sizes[0] / 10;                   // obs is [B,10]
    const int tiles = (B + 15) / 16;                  // 32768
    const int wavesN = (tiles + NT - 1) / NT;         // 8192
    const int grid  = (wavesN + NW - 1) / NW;         // 2048

    barriernet_kernel<<<grid, TPB, 0, stream>>>(obs, ws, b31, b32,
                                                (float*)d_out, B);
}